// Round 2
// baseline (300.869 us; speedup 1.0000x reference)
//
#include <hip/hip_runtime.h>
#include <hip/hip_bf16.h>
#include <cstddef>

// Problem constants (match reference)
#define B_   256
#define T_   2048
#define DIM_ 64
// THETA=0.1, MU=0, SIGMA=1
// sigma/sqrt(2*theta) = 1/sqrt(0.2)
#define OU_SCALE 2.2360679774997896f

// ---------------------------------------------------------------------------
// Kernel 1: per-(b,t) coefficient table (all transcendentals live here).
// coef[b*T+t] = { delta_bm, delta_ou*OU_SCALE, f_bm, f_ou }
//   delta_bm = sqrt(t_k - t_{k-1})                  (0 if invalid)
//   delta_ou = sqrt(exp(2θ t_k) - exp(2θ t_{k-1}))  (0 if invalid)
//   f_bm     = 1 / (sqrt(t_k) + 1e-8)
//   f_ou     = exp(-θ t_k) / (sqrt((1-exp(-2θ t_k))/(2θ)) + 1e-8)
// ---------------------------------------------------------------------------
__global__ void coef_kernel(const float* __restrict__ ts,
                            float4* __restrict__ coef) {
    int i = blockIdx.x * blockDim.x + threadIdx.x;
    if (i >= B_ * T_) return;
    int t = i & (T_ - 1);
    float tk = ts[i];
    float tp = (t == 0) ? 0.0f : ts[i - 1];
    float dt = tk - tp;

    float db = sqrtf(dt);
    // exp(2θ t_k) - exp(2θ t_p) = exp(2θ t_p) * expm1(2θ dt)   (more accurate)
    float e2p = expf(0.2f * tp);
    float dou = sqrtf(e2p * expm1f(0.2f * dt));

    float cb = (db  <= 0.0f) ? 0.0f : db;             // * sqrt(sigma)=1
    float co = (dou <= 0.0f) ? 0.0f : dou * OU_SCALE;

    float fb = 1.0f / (sqrtf(tk) + 1e-8f);
    float em = expf(-0.1f * tk);                       // exp(-θ t)
    float one_m = -expm1f(-0.2f * tk);                 // 1 - exp(-2θ t)
    float fo = em / (sqrtf(one_m * 5.0f) + 1e-8f);     // /0.2 == *5

    coef[i] = make_float4(cb, co, fb, fo);
}

// ---------------------------------------------------------------------------
// Kernel 2: the time scan. One 64-thread block per batch b; thread d owns the
// (b,d) chain. Coef loads are wave-uniform -> scalar loads. Noise loads are
// fully coalesced (64 lanes x 4B = 256B per step). Unroll=32 for memory-level
// parallelism (loads are independent; only the accumulator is a dep chain).
// Output stored as FP32 (reference output dtype is float32).
// ---------------------------------------------------------------------------
#define UNROLL 32

__global__ __launch_bounds__(64) void scan_kernel(
        const float4* __restrict__ coef,
        const float* __restrict__ noise,
        float* __restrict__ out) {
    const int b = blockIdx.x;
    const int d = threadIdx.x;
    const bool ou_half = (d >= (DIM_ / 2));

    const float*  np_ = noise + (size_t)b * T_ * DIM_ + d;
    float*        op  = out   + (size_t)b * T_ * DIM_ + d;
    const float4* cp  = coef  + (size_t)b * T_;

    float acc = 0.0f;

    for (int t0 = 0; t0 < T_; t0 += UNROLL) {
        float  v[UNROLL];
        float4 c[UNROLL];
#pragma unroll
        for (int u = 0; u < UNROLL; ++u)
            v[u] = np_[(size_t)(t0 + u) * DIM_];
#pragma unroll
        for (int u = 0; u < UNROLL; ++u)
            c[u] = cp[t0 + u];
#pragma unroll
        for (int u = 0; u < UNROLL; ++u) {
            float delta = ou_half ? c[u].y : c[u].x;
            float f     = ou_half ? c[u].w : c[u].z;
            acc = fmaf(delta, v[u], acc);
            op[(size_t)(t0 + u) * DIM_] = acc * f;
        }
    }
}

// ---------------------------------------------------------------------------
extern "C" void kernel_launch(void* const* d_in, const int* in_sizes, int n_in,
                              void* d_out, int out_size, void* d_ws, size_t ws_size,
                              hipStream_t stream) {
    const float* ts    = (const float*)d_in[0];   // [B,T,1] fp32
    const float* noise = (const float*)d_in[1];   // [B,T,DIM] fp32
    float* out = (float*)d_out;                   // [B,T,DIM] fp32
    float4* coef = (float4*)d_ws;                 // 8 MB scratch

    int n = B_ * T_;
    coef_kernel<<<(n + 255) / 256, 256, 0, stream>>>(ts, coef);
    scan_kernel<<<B_, DIM_, 0, stream>>>(coef, noise, out);
}

// Round 3
// 273.149 us; speedup vs baseline: 1.1015x; 1.1015x over previous
//
#include <hip/hip_runtime.h>
#include <hip/hip_bf16.h>
#include <cstddef>

// Problem constants (match reference)
#define B_   256
#define T_   2048
#define DIM_ 64
#define C_   16            // chunks along T
#define L_   (T_ / C_)     // 128 steps per chunk
// THETA=0.1, MU=0, SIGMA=1 ; sigma/sqrt(2*theta) = 1/sqrt(0.2)
#define OU_SCALE 2.2360679774997896f

// ---------------------------------------------------------------------------
// Kernel 1: per-(b,t) coefficient table (all transcendentals live here).
// coef[b*T+t] = { delta_bm, delta_ou*OU_SCALE, f_bm, f_ou }
// ---------------------------------------------------------------------------
__global__ void coef_kernel(const float* __restrict__ ts,
                            float4* __restrict__ coef) {
    int i = blockIdx.x * blockDim.x + threadIdx.x;
    if (i >= B_ * T_) return;
    int t = i & (T_ - 1);
    float tk = ts[i];
    float tp = (t == 0) ? 0.0f : ts[i - 1];
    float dt = tk - tp;

    float db = sqrtf(dt);
    float e2p = expf(0.2f * tp);
    float dou = sqrtf(e2p * expm1f(0.2f * dt));

    float cb = (db  <= 0.0f) ? 0.0f : db;
    float co = (dou <= 0.0f) ? 0.0f : dou * OU_SCALE;

    float fb = 1.0f / (sqrtf(tk) + 1e-8f);
    float em = expf(-0.1f * tk);                   // exp(-θ t)
    float one_m = -expm1f(-0.2f * tk);             // 1 - exp(-2θ t)
    float fo = em / (sqrtf(one_m * 5.0f) + 1e-8f); // /(2θ) == *5

    coef[i] = make_float4(cb, co, fb, fo);
}

// ---------------------------------------------------------------------------
// Pass 1: per-(b,chunk) weighted partial sums. Grid = B*C single-wave blocks
// (16 waves/CU) so HBM latency is hidden by TLP, not compiler-fragile ILP.
// ---------------------------------------------------------------------------
#define UN 16

__global__ __launch_bounds__(64) void partial_kernel(
        const float4* __restrict__ coef,
        const float* __restrict__ noise,
        float* __restrict__ partials) {
    const int b = blockIdx.x >> 4;       // / C_
    const int c = blockIdx.x & (C_ - 1);
    const int d = threadIdx.x;
    const bool ou = (d >= DIM_ / 2);

    const float*  np_ = noise + ((size_t)b * T_ + (size_t)c * L_) * DIM_ + d;
    const float4* cp  = coef + (size_t)b * T_ + c * L_;

    float acc = 0.0f;
    for (int t0 = 0; t0 < L_; t0 += UN) {
        float  v[UN];
        float4 cc[UN];
#pragma unroll
        for (int u = 0; u < UN; ++u) v[u] = np_[(size_t)(t0 + u) * DIM_];
#pragma unroll
        for (int u = 0; u < UN; ++u) cc[u] = cp[t0 + u];
#pragma unroll
        for (int u = 0; u < UN; ++u) {
            float delta = ou ? cc[u].y : cc[u].x;
            acc = fmaf(delta, v[u], acc);
        }
    }
    partials[(size_t)blockIdx.x * DIM_ + d] = acc;
}

// ---------------------------------------------------------------------------
// Pass 2: base = sum of preceding chunk partials, then replay chunk scan and
// write normalized output.
// ---------------------------------------------------------------------------
__global__ __launch_bounds__(64) void final_kernel(
        const float4* __restrict__ coef,
        const float* __restrict__ noise,
        const float* __restrict__ partials,
        float* __restrict__ out) {
    const int b = blockIdx.x >> 4;
    const int c = blockIdx.x & (C_ - 1);
    const int d = threadIdx.x;
    const bool ou = (d >= DIM_ / 2);

    const float*  np_ = noise + ((size_t)b * T_ + (size_t)c * L_) * DIM_ + d;
    const float4* cp  = coef + (size_t)b * T_ + c * L_;
    float*        op  = out + ((size_t)b * T_ + (size_t)c * L_) * DIM_ + d;
    const float*  pp  = partials + (size_t)(b << 4) * DIM_ + d;

    // exclusive prefix of chunk partials (block-uniform trip count, <=15
    // independent coalesced loads)
    float base = 0.0f;
    for (int k = 0; k < c; ++k) base += pp[(size_t)k * DIM_];

    float acc = base;
    for (int t0 = 0; t0 < L_; t0 += UN) {
        float  v[UN];
        float4 cc[UN];
#pragma unroll
        for (int u = 0; u < UN; ++u) v[u] = np_[(size_t)(t0 + u) * DIM_];
#pragma unroll
        for (int u = 0; u < UN; ++u) cc[u] = cp[t0 + u];
#pragma unroll
        for (int u = 0; u < UN; ++u) {
            float delta = ou ? cc[u].y : cc[u].x;
            float f     = ou ? cc[u].w : cc[u].z;
            acc = fmaf(delta, v[u], acc);
            op[(size_t)(t0 + u) * DIM_] = acc * f;
        }
    }
}

// ---------------------------------------------------------------------------
extern "C" void kernel_launch(void* const* d_in, const int* in_sizes, int n_in,
                              void* d_out, int out_size, void* d_ws, size_t ws_size,
                              hipStream_t stream) {
    const float* ts    = (const float*)d_in[0];   // [B,T,1] fp32
    const float* noise = (const float*)d_in[1];   // [B,T,DIM] fp32
    float* out = (float*)d_out;                   // [B,T,DIM] fp32

    float4* coef     = (float4*)d_ws;                       // 8 MB
    float*  partials = (float*)((char*)d_ws + (size_t)B_ * T_ * 16); // 1 MB

    int n = B_ * T_;
    coef_kernel<<<(n + 255) / 256, 256, 0, stream>>>(ts, coef);
    partial_kernel<<<B_ * C_, DIM_, 0, stream>>>(coef, noise, partials);
    final_kernel<<<B_ * C_, DIM_, 0, stream>>>(coef, noise, partials, out);
}

// Round 4
// 253.396 us; speedup vs baseline: 1.1873x; 1.0780x over previous
//
#include <hip/hip_runtime.h>
#include <cstddef>

// Problem constants (match reference)
#define B_   256
#define T_   2048
#define DIM_ 64
#define NW   16          // waves per block (block = 1024 threads)
#define CH   (T_ / NW)   // 128 steps per wave-chunk
// THETA=0.1, MU=0, SIGMA=1 ; sigma/sqrt(2*theta) = sqrt(5)
#define OU_SCALE 2.2360679774997896f

// One block per batch row b. 16 waves:
//   Stage 0: coef table for row b -> LDS (all transcendentals, 2 entries/thread)
//   Phase A: wave w computes weighted partial sum of chunk w (float4 loads)
//   Phase B: base from LDS partials, replay chunk (noise re-read is L2/L3-hot),
//            write normalized output.
__global__ __launch_bounds__(1024) void fused_kernel(
        const float* __restrict__ ts,
        const float* __restrict__ noise,
        float* __restrict__ out)
{
    __shared__ float4 cofs[T_];       // 32 KB {delta_bm, delta_ou*sqrt5, f_bm, f_ou}
    __shared__ float4 par4[NW * 16];  // 4 KB chunk partials [chunk][dim/4]

    const int b   = blockIdx.x;
    const int tid = threadIdx.x;
    const int w   = tid >> 6;   // wave id = chunk id
    const int l   = tid & 63;   // lane = dim (phase B)

    // ---- Stage 0: per-(b,t) coefficients into LDS ----
    const float* tsb = ts + (size_t)b * T_;
    for (int t = tid; t < T_; t += 1024) {
        float tk = tsb[t];
        float tp = (t == 0) ? 0.0f : tsb[t - 1];
        float dt = tk - tp;

        float db  = sqrtf(dt);
        // exp(2θtk)-exp(2θtp) = exp(2θtp)*expm1(2θ dt)
        float dou = sqrtf(expf(0.2f * tp) * expm1f(0.2f * dt));

        float cb = (db  <= 0.0f) ? 0.0f : db;              // * sqrt(sigma)=1
        float co = (dou <= 0.0f) ? 0.0f : dou * OU_SCALE;

        float fb = 1.0f / (sqrtf(tk) + 1e-8f);
        float em = expf(-0.1f * tk);                       // exp(-θ t)
        float fo = em / (sqrtf(-expm1f(-0.2f * tk) * 5.0f) + 1e-8f);

        cofs[t] = make_float4(cb, co, fb, fo);
    }
    __syncthreads();

    const size_t rowbase = (size_t)b * T_ * DIM_;

    // ---- Phase A: weighted partial of chunk w (skip last chunk: unused) ----
    if (w != NW - 1) {
        const int  g   = l >> 4;            // step subgroup 0..3
        const int  dq  = (l & 15) << 2;     // dim quad base (all 4 same half)
        const bool ouA = (dq >= DIM_ / 2);
        const int  tb  = w * CH;
        float4 a = make_float4(0.f, 0.f, 0.f, 0.f);
#pragma unroll 8
        for (int i = 0; i < CH / 4; ++i) {
            const int t = tb + (i << 2) + g;
            const float4 v = *(const float4*)(noise + rowbase + (size_t)t * DIM_ + dq);
            const float4 c = cofs[t];
            const float delta = ouA ? c.y : c.x;
            a.x = fmaf(delta, v.x, a.x);
            a.y = fmaf(delta, v.y, a.y);
            a.z = fmaf(delta, v.z, a.z);
            a.w = fmaf(delta, v.w, a.w);
        }
        // combine the 4 step-subgroups (lanes sharing l&15)
        a.x += __shfl_xor(a.x, 16); a.y += __shfl_xor(a.y, 16);
        a.z += __shfl_xor(a.z, 16); a.w += __shfl_xor(a.w, 16);
        a.x += __shfl_xor(a.x, 32); a.y += __shfl_xor(a.y, 32);
        a.z += __shfl_xor(a.z, 32); a.w += __shfl_xor(a.w, 32);
        if (l < 16) par4[w * 16 + l] = a;
    }
    __syncthreads();

    // ---- Phase B: exclusive prefix over chunk partials, replay, write ----
    const float* parf = (const float*)par4;
    float acc = 0.0f;
    for (int k = 0; k < w; ++k) acc += parf[k * DIM_ + l];

    const bool ou  = (l >= DIM_ / 2);
    const float* np_ = noise + rowbase + l;
    float*       op  = out   + rowbase + l;
    const int tb = w * CH;
#pragma unroll 8
    for (int t = tb; t < tb + CH; ++t) {
        float v = np_[(size_t)t * DIM_];
        float4 c = cofs[t];
        float delta = ou ? c.y : c.x;
        float f     = ou ? c.w : c.z;
        acc = fmaf(delta, v, acc);
        op[(size_t)t * DIM_] = acc * f;
    }
}

// ---------------------------------------------------------------------------
extern "C" void kernel_launch(void* const* d_in, const int* in_sizes, int n_in,
                              void* d_out, int out_size, void* d_ws, size_t ws_size,
                              hipStream_t stream) {
    const float* ts    = (const float*)d_in[0];   // [B,T,1] fp32
    const float* noise = (const float*)d_in[1];   // [B,T,DIM] fp32
    float* out = (float*)d_out;                   // [B,T,DIM] fp32
    (void)d_ws; (void)ws_size;

    fused_kernel<<<B_, NW * 64, 0, stream>>>(ts, noise, out);
}